// Round 4
// baseline (424.806 us; speedup 1.0000x reference)
//
#include <hip/hip_runtime.h>
#include <hip/hip_bf16.h>
#include <cmath>

// Problem constants
#define B_    4
#define T_    1000000
#define E_    8
#define C_    128
#define NCH   512        // fused conv output channels (both branches, 2*256)
#define KK    4096       // GEMM K = E * kernel (8*512); windows are contiguous rows
#define TOUT  1953       // (1e6 - 512)/512 + 1
#define TP    1956       // padded t stride (mult of 4) for aligned float4 stores
#define NT2   31         // ceil(1953/64) tiles of 64 along t

typedef __attribute__((ext_vector_type(8))) short bf16x8;   // 8 bf16 = 4 VGPRs
typedef __attribute__((ext_vector_type(4))) float f32x4;

__device__ __forceinline__ float sigmoidf_(float v) { return 1.f / (1.f + __expf(-v)); }

// ---------------------------------------------------------------------------
// Weight prep (x conversion is fused into the GEMM — stride==kernel so conv
// windows are non-overlapping and the A matrix is a pure reshape of x).
// Frag chunk = 16 rows x 32 k as [lane][8], lane = (k>>3&3)*16 + (row&15).
// Wn2: [nt=n/16][kc=k/32][lane][8]
__global__ __launch_bounds__(256) void prep_inputs(
    const float* __restrict__ wc, const float* __restrict__ bc,
    const float* __restrict__ wm, const float* __restrict__ bm,
    __hip_bfloat16* __restrict__ Wn2, float* __restrict__ bias_t) {
  __shared__ float row[KK];
  const int n = blockIdx.x, br = n >> 8, o = n & 255;
  const float* wsrc = (br ? wm : wc) + (size_t)o * KK;
  for (int i = threadIdx.x; i < KK; i += 256) row[i] = wsrc[i];   // [e][kpos]
  __syncthreads();
  const int nt = n >> 4, nr = n & 15;
  for (int k = threadIdx.x; k < KK; k += 256) {
    int kpos = k >> 3, e = k & 7;                 // W[n][k] with k = kpos*8+e
    size_t addr = (((size_t)nt * 128 + (k >> 5)) * 64
                   + (size_t)((k >> 3) & 3) * 16 + nr) * 8 + (k & 7);
    Wn2[addr] = __float2bfloat16(row[e * 512 + kpos]);
  }
  if (threadIdx.x == 0) bias_t[n] = (br ? bm : bc)[o];
}

// ---------------------------------------------------------------------------
// Kernel C (R8): barrier-free LDS-free fused GEMM, 4-deep register prefetch.
// C[t,n] = sum_k A[t,k]W[n,k], A[t,k] = bf16(x[b, t*512 + k/8, k%8]).
// Block = 512 thr = 8 waves (4 t-waves x 2 n-waves), tile 128x128, wave tile
// 32t x 64n (acc 2x4). Waves are fully INDEPENDENT: no LDS, no barriers, no
// inline-asm waits — R2/R3 showed per-step barriers at 1 block/CU convoy on
// HBM latency (5400+ cyc/step, MfmaUtil 8-9%); R0 showed the barrier-free
// register structure with compiler-scheduled counted s_waitcnt works.
// K is split into 128 substeps of BK=32 (one kc chunk). A 4-deep load-set
// ring (substeps s..s+3 in flight, ~190 VGPR, fits the 256-VGPR budget at
// the block-limited 8-waves/CU occupancy) gives ~1240 cyc of latency cover
// per wave (> ~900 cyc HBM), x2 independent waves per SIMD.
//   A: per substep 4x global_load_dwordx4 (fp32, 16 rows/instr scatter —
//      prep_inputs proved this pattern sustains BW once latency is hidden),
//      cvt->bf16 in-reg at consume time. wn-twin waves duplicate A loads;
//      L1 serves the repeat.
//   B: per substep 4x coalesced global_load_dwordx4 from frag-ordered Wn2
//      (4 MB, L2-resident; the 4 nb-blocks of one (t,b) group share an XCD
//      via the swizzle, so x panels are fetched from HBM once per XCD).
// Tail: the last ring refills over-issue substeps 128..131: A stays inside
// x (max idx 31,999,647 < 32M); B runs ~2-4 KB past Wn2 into bias_t/u2
// (allocated workspace, values never consumed).
__global__ __launch_bounds__(512, 2) void mfma_gemm(
    const float* __restrict__ x, const __hip_bfloat16* __restrict__ Wn2,
    float* __restrict__ u2) {
  const int tid  = threadIdx.x;
  const int lane = tid & 63, wave = tid >> 6;
  const int wt = wave & 3, wn = wave >> 2;

  // Swizzle: L = xcd + 8*(nb + 4*sh); s = sh*8 + xcd = (t,b) group 0..63.
  const int L   = blockIdx.x;
  const int xcd = L & 7;
  const int r   = L >> 3;
  const int nb  = r & 3;
  const int sh  = r >> 2;                 // 0..7
  const int s   = sh * 8 + xcd;           // 0..63
  const int tblk = s & 15, b = s >> 4;
  const int t0 = tblk * 128, n0 = nb * 128;

  // A rows owned by this (wave,lane): frag i covers row rAi, i in {0,1}.
  int rA0 = t0 + wt * 32 + (lane & 15);
  int rA1 = rA0 + 16;
  if (rA0 >= TOUT) rA0 = 0;   // tblk=15 tail rows: clamp (never stored)
  if (rA1 >= TOUT) rA1 = 0;
  const int kA = (lane >> 4) * 8;          // 0,8,16,24 floats within 32-k chunk
  const float* pA0 = x + (size_t)b * 8000000ull + (size_t)rA0 * KK + kA;
  const float* pA1 = x + (size_t)b * 8000000ull + (size_t)rA1 * KK + kA;
  // substep s: frag i = 2 x float4 at pAi + s*32 + {0,4}

  // B frag (j) base pointers, frag-ordered coalesced; substep s at +s*512.
  const __hip_bfloat16* gB[4];
#pragma unroll
  for (int j = 0; j < 4; ++j)
    gB[j] = Wn2 + ((size_t)(nb * 8 + wn * 4 + j) * 128) * 512 + (size_t)lane * 8;

  f32x4 acc[2][4];
#pragma unroll
  for (int i = 0; i < 2; ++i)
#pragma unroll
    for (int j = 0; j < 4; ++j) acc[i][j] = (f32x4)(0.0f);

  // 4-deep prefetch ring (all indices compile-time after unroll — rule #20).
  float4 Ar[4][2][2];   // [set][i][half]
  bf16x8 Br[4][4];      // [set][j]

#define LOADSET(SET, SS)                                                  \
  do {                                                                    \
    const int ss_ = (SS);                                                 \
    const float* p0_ = pA0 + (size_t)ss_ * 32;                            \
    const float* p1_ = pA1 + (size_t)ss_ * 32;                            \
    Ar[SET][0][0] = *(const float4*)(p0_);                                \
    Ar[SET][0][1] = *(const float4*)(p0_ + 4);                            \
    Ar[SET][1][0] = *(const float4*)(p1_);                                \
    Ar[SET][1][1] = *(const float4*)(p1_ + 4);                            \
    Br[SET][0] = *(const bf16x8*)(gB[0] + (size_t)ss_ * 512);             \
    Br[SET][1] = *(const bf16x8*)(gB[1] + (size_t)ss_ * 512);             \
    Br[SET][2] = *(const bf16x8*)(gB[2] + (size_t)ss_ * 512);             \
    Br[SET][3] = *(const bf16x8*)(gB[3] + (size_t)ss_ * 512);             \
  } while (0)

#define CVTMFMA(SET)                                                      \
  do {                                                                    \
    bf16x8 aF_[2];                                                        \
    _Pragma("unroll")                                                     \
    for (int i_ = 0; i_ < 2; ++i_) {                                      \
      union { __hip_bfloat16 h[8]; bf16x8 v; } u_;                        \
      float4 lo_ = Ar[SET][i_][0], hi_ = Ar[SET][i_][1];                  \
      u_.h[0] = __float2bfloat16(lo_.x); u_.h[1] = __float2bfloat16(lo_.y); \
      u_.h[2] = __float2bfloat16(lo_.z); u_.h[3] = __float2bfloat16(lo_.w); \
      u_.h[4] = __float2bfloat16(hi_.x); u_.h[5] = __float2bfloat16(hi_.y); \
      u_.h[6] = __float2bfloat16(hi_.z); u_.h[7] = __float2bfloat16(hi_.w); \
      aF_[i_] = u_.v;                                                     \
    }                                                                     \
    _Pragma("unroll")                                                     \
    for (int i_ = 0; i_ < 2; ++i_)                                        \
      _Pragma("unroll")                                                   \
      for (int j_ = 0; j_ < 4; ++j_)                                      \
        acc[i_][j_] = __builtin_amdgcn_mfma_f32_16x16x32_bf16(            \
            aF_[i_], Br[SET][j_], acc[i_][j_], 0, 0, 0);                  \
  } while (0)

  // Prologue: fill the ring with substeps 0..3.
  LOADSET(0, 0);
  LOADSET(1, 1);
  LOADSET(2, 2);
  LOADSET(3, 3);

#pragma unroll 1
  for (int it = 0; it < 32; ++it) {
    const int base = it * 4;
    CVTMFMA(0); LOADSET(0, base + 4);
    CVTMFMA(1); LOADSET(1, base + 5);
    CVTMFMA(2); LOADSET(2, base + 6);
    CVTMFMA(3); LOADSET(3, base + 7);
  }
  // (iterations consume substeps 0..127; the final refills 128..131 are
  //  over-issued and never consumed — addresses stay inside x / workspace)

#undef LOADSET
#undef CVTMFMA

  // Epilogue. C/D layout: col = lane&15, row = (lane>>4)*4 + reg.
  const int crow = (lane >> 4) * 4;
  const int ccol = lane & 15;
#pragma unroll
  for (int j = 0; j < 4; ++j) {
    int n = n0 + wn * 64 + j * 16 + ccol;
    float* urow = u2 + ((size_t)n * B_ + b) * TP;
#pragma unroll
    for (int i = 0; i < 2; ++i) {
      int t = t0 + wt * 32 + i * 16 + crow;    // mult of 4
      if (t < TOUT) *(f32x4*)(urow + t) = acc[i][j];  // may touch pad [1953,1956)
    }
  }
}

// ---------------------------------------------------------------------------
// Kernel 2: bias + GLU (on load from u2) -> 1x1 share conv + leaky.
// br==1: store h_main; br==0: per-tile max over t -> gct_part.
__global__ __launch_bounds__(256) void share_act(
    const float* __restrict__ u2, const float* __restrict__ bias_t,
    const float* __restrict__ wsc, const float* __restrict__ bsc,
    const float* __restrict__ wsm, const float* __restrict__ bsm,
    float* __restrict__ hmain, float* __restrict__ gct_part) {
  __shared__ float Wl[128 * 132];   // Wl[cp*132 + cout] = ws[cout, cp]
  __shared__ float ul[128 * 68];    // ul[cp*68 + t]
  const int tid  = threadIdx.x;
  const int tile = blockIdx.x;      // 0..30
  const int b    = blockIdx.y;
  const int br   = blockIdx.z;
  const int t0   = tile * 64;
  const float* ws = br ? wsm : wsc;
  const float* bs = br ? bsm : bsc;

  for (int g = tid; g < 16384; g += 256) {
    int co = g >> 7, cp = g & 127;
    Wl[cp * 132 + co] = ws[g];
  }
  const size_t base_v = ((size_t)(br * 256) * B_ + b) * TP;
  const size_t base_g = ((size_t)(br * 256 + 128) * B_ + b) * TP;
  for (int g = tid; g < 8192; g += 256) {
    int cp = g >> 6, t = g & 63;
    float v = 0.f;
    if (t0 + t < TOUT) {
      float va = u2[base_v + (size_t)cp * B_ * TP + t0 + t] + bias_t[br * 256 + cp];
      float vg = u2[base_g + (size_t)cp * B_ * TP + t0 + t] + bias_t[br * 256 + 128 + cp];
      v = va * sigmoidf_(vg);
    }
    ul[cp * 68 + t] = v;
  }
  __syncthreads();

  const int ty = tid >> 4, tx = tid & 15;  // c-groups x t-groups
  float acc[8][4];
#pragma unroll
  for (int i = 0; i < 8; ++i)
#pragma unroll
    for (int j = 0; j < 4; ++j) acc[i][j] = 0.f;

  for (int cp = 0; cp < 128; ++cp) {
    float4 a0 = *(const float4*)&Wl[cp*132 + ty*4];
    float4 a1 = *(const float4*)&Wl[cp*132 + 64 + ty*4];
    float4 b4 = *(const float4*)&ul[cp*68 + tx*4];
    float av[8] = {a0.x,a0.y,a0.z,a0.w,a1.x,a1.y,a1.z,a1.w};
    float bv[4] = {b4.x,b4.y,b4.z,b4.w};
#pragma unroll
    for (int i = 0; i < 8; ++i)
#pragma unroll
      for (int j = 0; j < 4; ++j) acc[i][j] = fmaf(av[i], bv[j], acc[i][j]);
  }

  float mloc[8];
#pragma unroll
  for (int i = 0; i < 8; ++i) mloc[i] = -INFINITY;
#pragma unroll
  for (int i = 0; i < 8; ++i) {
    int c = (i < 4) ? (ty*4 + i) : (64 + ty*4 + (i - 4));
    float bias = bs[c];
#pragma unroll
    for (int j = 0; j < 4; ++j) {
      int t = t0 + tx*4 + j;
      if (t >= TOUT) continue;
      float v = acc[i][j] + bias;
      v = (v >= 0.f) ? v : 0.01f * v;
      if (br == 1) {
        hmain[((size_t)b * 128 + c) * TOUT + t] = v;
      } else {
        mloc[i] = fmaxf(mloc[i], v);
      }
    }
  }
  if (br == 0) {
    __syncthreads();               // done reading ul; reuse as reduction buffer
    float* red = ul;               // 128*16 region
#pragma unroll
    for (int i = 0; i < 8; ++i) {
      int c = (i < 4) ? (ty*4 + i) : (64 + ty*4 + (i - 4));
      red[c * 16 + tx] = mloc[i];
    }
    __syncthreads();
    if (tid < 128) {
      float m = -INFINITY;
#pragma unroll
      for (int k = 0; k < 16; ++k) m = fmaxf(m, red[tid * 16 + k]);
      gct_part[((size_t)b * 128 + tid) * NT2 + tile] = m;
    }
  }
}

// ---------------------------------------------------------------------------
// Kernel 3: gct = max over tiles; q = tanh(gct @ Wp^T + bp). One block per b.
__global__ void gct_q(const float* __restrict__ gct_part, const float* __restrict__ wp,
                      const float* __restrict__ bp, float* __restrict__ q) {
  int b = blockIdx.x, tid = threadIdx.x;   // 128 threads
  __shared__ float g[128];
  float m = -INFINITY;
  for (int tl = 0; tl < NT2; ++tl) m = fmaxf(m, gct_part[((size_t)b * 128 + tid) * NT2 + tl]);
  g[tid] = m;
  __syncthreads();
  float s = bp[tid];
  for (int c = 0; c < 128; ++c) s = fmaf(g[c], wp[tid * 128 + c], s);
  q[b * 128 + tid] = tanhf(s);
}

// ---------------------------------------------------------------------------
// Kernel 4: gate[t] = sigmoid(sum_c h*q); out_part = per-tile max_t h*gate.
__global__ __launch_bounds__(256) void gate_max(
    const float* __restrict__ hmain, const float* __restrict__ q,
    float* __restrict__ out_part) {
  __shared__ float hl[128 * 68];
  __shared__ float ql[128];
  __shared__ float red[256];
  __shared__ float gl[64];
  int tid = threadIdx.x, tile = blockIdx.x, b = blockIdx.y;
  int t0 = tile * 64;
  for (int g = tid; g < 8192; g += 256) {
    int c = g >> 6, t = g & 63;
    hl[c * 68 + t] = (t0 + t < TOUT) ? hmain[((size_t)b * 128 + c) * TOUT + t0 + t] : 0.f;
  }
  if (tid < 128) ql[tid] = q[b * 128 + tid];
  __syncthreads();
  {
    int t = tid & 63, cy = tid >> 6;
    float s = 0.f;
#pragma unroll
    for (int cc = 0; cc < 32; ++cc) s = fmaf(hl[(cy * 32 + cc) * 68 + t], ql[cy * 32 + cc], s);
    red[cy * 64 + t] = s;
  }
  __syncthreads();
  if (tid < 64) {
    float s = red[tid] + red[64 + tid] + red[128 + tid] + red[192 + tid];
    gl[tid] = sigmoidf_(s);
  }
  __syncthreads();
  {
    int c = tid >> 1, th = tid & 1;
    float m = -INFINITY;
#pragma unroll
    for (int tt = 0; tt < 32; ++tt) {
      int t = th * 32 + tt;
      if (t0 + t < TOUT) m = fmaxf(m, hl[c * 68 + t] * gl[t]);
    }
    red[c * 2 + th] = m;
  }
  __syncthreads();
  if (tid < 128) out_part[((size_t)b * 128 + tid) * NT2 + tile] = fmaxf(red[tid * 2], red[tid * 2 + 1]);
}

// ---------------------------------------------------------------------------
// Kernel 5: final max over tiles -> d_out (B,C) row-major.
__global__ void final_max(const float* __restrict__ out_part, float* __restrict__ out) {
  int idx = blockIdx.x * 256 + threadIdx.x;
  if (idx < 512) {
    float m = -INFINITY;
    for (int tl = 0; tl < NT2; ++tl) m = fmaxf(m, out_part[(size_t)idx * NT2 + tl]);
    out[idx] = m;
  }
}

// ---------------------------------------------------------------------------
extern "C" void kernel_launch(void* const* d_in, const int* in_sizes, int n_in,
                              void* d_out, int out_size, void* d_ws, size_t ws_size,
                              hipStream_t stream) {
  const float* x      = (const float*)d_in[0];
  const float* ctx_w  = (const float*)d_in[1];
  const float* ctx_b  = (const float*)d_in[2];
  const float* ctx_sw = (const float*)d_in[3];
  const float* ctx_sb = (const float*)d_in[4];
  const float* main_w = (const float*)d_in[5];
  const float* main_b = (const float*)d_in[6];
  const float* main_sw= (const float*)d_in[7];
  const float* main_sb= (const float*)d_in[8];
  const float* gp_w   = (const float*)d_in[9];
  const float* gp_b   = (const float*)d_in[10];

  char* w = (char*)d_ws;
  __hip_bfloat16* Wn2 = (__hip_bfloat16*)(w);              // 512*4096*2 = 4,194,304
  float* bias_t  = (float*)(w + 4194304);                  // 512*4 = 2048
  float* u2      = (float*)(w + 4196352);                  // 512*4*TP*4 = 16,023,552
  float* hmain   = (float*)(w + 20219904);                 // 4*128*1953*4 = 3,999,744
  float* gct_part= (float*)(w + 24219648);                 // 4*128*31*4 = 63,488
  float* q       = (float*)(w + 24283136);                 // 512*4
  float* out_part= (float*)(w + 24285184);                 // 63,488

  prep_inputs<<<NCH, 256, 0, stream>>>(ctx_w, ctx_b, main_w, main_b, Wn2, bias_t);
  mfma_gemm<<<256, 512, 0, stream>>>(x, Wn2, u2);
  share_act<<<dim3(NT2, B_, 2), 256, 0, stream>>>(u2, bias_t, ctx_sw, ctx_sb,
                                                  main_sw, main_sb, hmain, gct_part);
  gct_q<<<B_, 128, 0, stream>>>(gct_part, gp_w, gp_b, q);
  gate_max<<<dim3(NT2, B_), 256, 0, stream>>>(hmain, q, out_part);
  final_max<<<2, 256, 0, stream>>>(out_part, (float*)d_out);
}

// Round 5
// 340.309 us; speedup vs baseline: 1.2483x; 1.2483x over previous
//
#include <hip/hip_runtime.h>
#include <hip/hip_bf16.h>
#include <cmath>

// Problem constants
#define B_    4
#define T_    1000000
#define E_    8
#define C_    128
#define NCH   512        // fused conv output channels (both branches, 2*256)
#define KK    4096       // GEMM K = E * kernel (8*512); windows are contiguous rows
#define TOUT  1953       // (1e6 - 512)/512 + 1
#define TP    1956       // padded t stride (mult of 4) for aligned float4 stores
#define NT2   31         // ceil(1953/64) tiles of 64 along t

typedef __attribute__((ext_vector_type(8))) short bf16x8;   // 8 bf16 = 4 VGPRs
typedef __attribute__((ext_vector_type(4))) float f32x4;

__device__ __forceinline__ float sigmoidf_(float v) { return 1.f / (1.f + __expf(-v)); }

// async 16B/lane global->LDS copy: LDS dest = uniform base + lane*16.
// GLOBAL source is per-lane (guide: pre-swizzled-source pattern, m173).
__device__ __forceinline__ void gload_lds16(const void* g, void* l) {
  __builtin_amdgcn_global_load_lds(
      (const __attribute__((address_space(1))) void*)g,
      (__attribute__((address_space(3))) void*)l, 16, 0, 0);
}

// ---------------------------------------------------------------------------
// Weight prep (x conversion is fused into the GEMM — stride==kernel so conv
// windows are non-overlapping and the A matrix is a pure reshape of x).
// Frag chunk = 16 rows x 32 k as [lane][8], lane = (k>>3&3)*16 + (row&15).
// Wn2: [nt=n/16][kc=k/32][lane][8]
__global__ __launch_bounds__(256) void prep_inputs(
    const float* __restrict__ wc, const float* __restrict__ bc,
    const float* __restrict__ wm, const float* __restrict__ bm,
    __hip_bfloat16* __restrict__ Wn2, float* __restrict__ bias_t) {
  __shared__ float row[KK];
  const int n = blockIdx.x, br = n >> 8, o = n & 255;
  const float* wsrc = (br ? wm : wc) + (size_t)o * KK;
  for (int i = threadIdx.x; i < KK; i += 256) row[i] = wsrc[i];   // [e][kpos]
  __syncthreads();
  const int nt = n >> 4, nr = n & 15;
  for (int k = threadIdx.x; k < KK; k += 256) {
    int kpos = k >> 3, e = k & 7;                 // W[n][k] with k = kpos*8+e
    size_t addr = (((size_t)nt * 128 + (k >> 5)) * 64
                   + (size_t)((k >> 3) & 3) * 16 + nr) * 8 + (k & 7);
    Wn2[addr] = __float2bfloat16(row[e * 512 + kpos]);
  }
  if (threadIdx.x == 0) bias_t[n] = (br ? bm : bc)[o];
}

// ---------------------------------------------------------------------------
// Kernel C (R9): fused GEMM, R1-proven mechanics, ZERO VGPR-destination loads
// in the loop. C[t,n] = sum_k A[t,k]W[n,k], A[t,k] = bf16(x[b,t*512+k/8,k%8]).
//
// Lesson from R2/R3/R4: any staging load whose result lands in a VGPR gets
// sunk by LLVM to its use point (R4: VGPR=48 proves the "4-deep ring" was
// eliminated), serializing on HBM latency. R1 (everything via global_load_lds,
// one __syncthreads per step) measured ~56us. So: ALL staging here is
// global_load_lds (void result, side-effecting -> cannot be sunk).
//   A: staged as RAW FP32 into LDS tile [128 rows][64 k] (32 KB/buf), 4
//      instrs/wave/step. fp32->bf16 cvt happens at CONSUME time (ds_read
//      fp32 -> v_cvt -> MFMA A-frag). Numerically identical (same RNE cvt).
//   B: global_load_lds from frag-ordered Wn2 as before (2 instrs/wave/step).
// Bank conflicts (G4): [128][64] fp32 row-major read by 16 consecutive-row
// lanes is 16-way same-bank. Fix per rule #21 (both-sides-or-neither with
// gload_lds): LDS stays LINEAR; the per-lane GLOBAL source applies the
// inverse involution u = (lane&15) ^ (rowlocal&7) (16B-unit XOR within each
// row), and the ds_read applies the same XOR -> each bank serves exactly
// 8 dwords per b128 instr = conflict-free minimum.
// Loop: STAGE(next) -> COMPUTE(cur) -> __syncthreads (drains vmcnt+lgkm;
// the ~1500cy of ds_read+cvt+MFMA covers the staging latency). BK=64, 64
// steps. LDS 2*(32+16) = 96 KB -> 1 block/CU (as before).
// Grid 256 = 1 block/CU; XCD swizzle: the 4 nb-blocks of one (t,b) group
// share L%8 = XCD so x panels are fetched from HBM once per XCD.
__global__ __launch_bounds__(512, 2) void mfma_gemm(
    const float* __restrict__ x, const __hip_bfloat16* __restrict__ Wn2,
    float* __restrict__ u2) {
  __shared__ float Aldf[2][8192];          // 2 x 32 KB fp32 A-tile [128][64]
  __shared__ __hip_bfloat16 Bs[2][8192];   // 2 x 16 KB bf16 frag-chunks

  const int tid  = threadIdx.x;
  const int lane = tid & 63, wave = tid >> 6;
  const int wt = wave & 3, wn = wave >> 2;

  // Swizzle: L = xcd + 8*(nb + 4*sh); s = sh*8 + xcd = (t,b) group 0..63.
  const int L   = blockIdx.x;
  const int xcd = L & 7;
  const int r   = L >> 3;
  const int nb  = r & 3;
  const int sh  = r >> 2;                 // 0..7
  const int s   = sh * 8 + xcd;           // 0..63
  const int tblk = s & 15, b = s >> 4;
  const int t0 = tblk * 128, n0 = nb * 128;

  // ---- A staging sources: wave owns chunks m = wave*4+q (4 rows each).
  // Lane l of chunk m: local row rl = m*4 + (l>>4); the 16B it stores lands
  // at LDS unit (l&15) of that row, so it must carry LOGICAL unit
  // u = (l&15) ^ (rl&7)  (inverse swizzle on the global side).
  const float* pAsrc[4];
  int dstA[4];
#pragma unroll
  for (int q = 0; q < 4; ++q) {
    int m  = wave * 4 + q;
    int rl = m * 4 + (lane >> 4);
    int u  = (lane & 15) ^ (rl & 7);
    int rt = t0 + rl;
    if (rt >= TOUT) rt = 0;     // tblk=15 tail rows: clamp (never stored)
    pAsrc[q] = x + (size_t)b * 8000000ull + (size_t)rt * KK + u * 4;
    dstA[q]  = m * 256;         // floats: chunk m = rows [m*4, m*4+4)
  }
  // ---- B staging: wave stages chunk slots wave*2, wave*2+1 (kc = 2step,+1).
  const __hip_bfloat16* gB = Wn2 + ((size_t)(nb * 8 + wave) * 128) * 512
                             + (size_t)lane * 8;

  f32x4 acc[2][4];
#pragma unroll
  for (int i = 0; i < 2; ++i)
#pragma unroll
    for (int j = 0; j < 4; ++j) acc[i][j] = (f32x4)(0.0f);

  auto STAGE = [&](int buf, int step) {
#pragma unroll
    for (int q = 0; q < 4; ++q)
      gload_lds16(pAsrc[q] + (size_t)step * 64, &Aldf[buf][dstA[q]]);
    const __hip_bfloat16* g = gB + (size_t)step * 1024;
    gload_lds16(g,       &Bs[buf][(size_t)(wave * 2) * 512]);
    gload_lds16(g + 512, &Bs[buf][(size_t)(wave * 2 + 1) * 512]);
  };

  auto COMPUTE = [&](int buf) {
    const int lnlo = lane & 15;
    const int pb = ((lane >> 4) * 2) ^ (lnlo & 7);   // swizzled 16B-unit base
    bf16x8 aF[2][2], bF[4][2];
#pragma unroll
    for (int i = 0; i < 2; ++i) {
      const int Rb = wt * 32 + i * 16 + lnlo;        // tile-local A row
#pragma unroll
      for (int c = 0; c < 2; ++c) {
        const float* base = &Aldf[buf][Rb * 64 + c * 32];
        f32x4 q0 = *(const f32x4*)(base + (pb)      * 4);   // logical j=0..3
        f32x4 q1 = *(const f32x4*)(base + (pb ^ 1) * 4);    // logical j=4..7
        union { __hip_bfloat16 h[8]; bf16x8 v; } u_;
        u_.h[0] = __float2bfloat16(q0[0]); u_.h[1] = __float2bfloat16(q0[1]);
        u_.h[2] = __float2bfloat16(q0[2]); u_.h[3] = __float2bfloat16(q0[3]);
        u_.h[4] = __float2bfloat16(q1[0]); u_.h[5] = __float2bfloat16(q1[1]);
        u_.h[6] = __float2bfloat16(q1[2]); u_.h[7] = __float2bfloat16(q1[3]);
        aF[i][c] = u_.v;
      }
    }
#pragma unroll
    for (int j = 0; j < 4; ++j)
#pragma unroll
      for (int c = 0; c < 2; ++c)
        bF[j][c] = *(const bf16x8*)(&Bs[buf][(size_t)((wn * 4 + j) * 2 + c) * 512
                                             + (size_t)lane * 8]);
#pragma unroll
    for (int c = 0; c < 2; ++c)
#pragma unroll
      for (int i = 0; i < 2; ++i)
#pragma unroll
        for (int j = 0; j < 4; ++j)
          acc[i][j] = __builtin_amdgcn_mfma_f32_16x16x32_bf16(aF[i][c], bF[j][c],
                                                              acc[i][j], 0, 0, 0);
  };

  // Prologue: fill buffer 0 (barrier drains vmcnt per __syncthreads semantics).
  STAGE(0, 0);
  __syncthreads();

  int cur = 0;
#pragma unroll 1
  for (int step = 0; step < 64; ++step) {
    if (step + 1 < 64) STAGE(cur ^ 1, step + 1);  // issue next-tile loads first
    COMPUTE(cur);                                  // ds_read + cvt + 16 MFMA
    __syncthreads();                               // drains vmcnt(0)+lgkmcnt(0)
    cur ^= 1;
  }

  // Epilogue. C/D layout: col = lane&15, row = (lane>>4)*4 + reg.
  const int crow = (lane >> 4) * 4;
  const int ccol = lane & 15;
#pragma unroll
  for (int j = 0; j < 4; ++j) {
    int n = n0 + wn * 64 + j * 16 + ccol;
    float* urow = u2 + ((size_t)n * B_ + b) * TP;
#pragma unroll
    for (int i = 0; i < 2; ++i) {
      int t = t0 + wt * 32 + i * 16 + crow;    // mult of 4
      if (t < TOUT) *(f32x4*)(urow + t) = acc[i][j];  // may touch pad [1953,1956)
    }
  }
}

// ---------------------------------------------------------------------------
// Kernel 2: bias + GLU (on load from u2) -> 1x1 share conv + leaky.
// br==1: store h_main; br==0: per-tile max over t -> gct_part.
__global__ __launch_bounds__(256) void share_act(
    const float* __restrict__ u2, const float* __restrict__ bias_t,
    const float* __restrict__ wsc, const float* __restrict__ bsc,
    const float* __restrict__ wsm, const float* __restrict__ bsm,
    float* __restrict__ hmain, float* __restrict__ gct_part) {
  __shared__ float Wl[128 * 132];   // Wl[cp*132 + cout] = ws[cout, cp]
  __shared__ float ul[128 * 68];    // ul[cp*68 + t]
  const int tid  = threadIdx.x;
  const int tile = blockIdx.x;      // 0..30
  const int b    = blockIdx.y;
  const int br   = blockIdx.z;
  const int t0   = tile * 64;
  const float* ws = br ? wsm : wsc;
  const float* bs = br ? bsm : bsc;

  for (int g = tid; g < 16384; g += 256) {
    int co = g >> 7, cp = g & 127;
    Wl[cp * 132 + co] = ws[g];
  }
  const size_t base_v = ((size_t)(br * 256) * B_ + b) * TP;
  const size_t base_g = ((size_t)(br * 256 + 128) * B_ + b) * TP;
  for (int g = tid; g < 8192; g += 256) {
    int cp = g >> 6, t = g & 63;
    float v = 0.f;
    if (t0 + t < TOUT) {
      float va = u2[base_v + (size_t)cp * B_ * TP + t0 + t] + bias_t[br * 256 + cp];
      float vg = u2[base_g + (size_t)cp * B_ * TP + t0 + t] + bias_t[br * 256 + 128 + cp];
      v = va * sigmoidf_(vg);
    }
    ul[cp * 68 + t] = v;
  }
  __syncthreads();

  const int ty = tid >> 4, tx = tid & 15;  // c-groups x t-groups
  float acc[8][4];
#pragma unroll
  for (int i = 0; i < 8; ++i)
#pragma unroll
    for (int j = 0; j < 4; ++j) acc[i][j] = 0.f;

  for (int cp = 0; cp < 128; ++cp) {
    float4 a0 = *(const float4*)&Wl[cp*132 + ty*4];
    float4 a1 = *(const float4*)&Wl[cp*132 + 64 + ty*4];
    float4 b4 = *(const float4*)&ul[cp*68 + tx*4];
    float av[8] = {a0.x,a0.y,a0.z,a0.w,a1.x,a1.y,a1.z,a1.w};
    float bv[4] = {b4.x,b4.y,b4.z,b4.w};
#pragma unroll
    for (int i = 0; i < 8; ++i)
#pragma unroll
      for (int j = 0; j < 4; ++j) acc[i][j] = fmaf(av[i], bv[j], acc[i][j]);
  }

  float mloc[8];
#pragma unroll
  for (int i = 0; i < 8; ++i) mloc[i] = -INFINITY;
#pragma unroll
  for (int i = 0; i < 8; ++i) {
    int c = (i < 4) ? (ty*4 + i) : (64 + ty*4 + (i - 4));
    float bias = bs[c];
#pragma unroll
    for (int j = 0; j < 4; ++j) {
      int t = t0 + tx*4 + j;
      if (t >= TOUT) continue;
      float v = acc[i][j] + bias;
      v = (v >= 0.f) ? v : 0.01f * v;
      if (br == 1) {
        hmain[((size_t)b * 128 + c) * TOUT + t] = v;
      } else {
        mloc[i] = fmaxf(mloc[i], v);
      }
    }
  }
  if (br == 0) {
    __syncthreads();               // done reading ul; reuse as reduction buffer
    float* red = ul;               // 128*16 region
#pragma unroll
    for (int i = 0; i < 8; ++i) {
      int c = (i < 4) ? (ty*4 + i) : (64 + ty*4 + (i - 4));
      red[c * 16 + tx] = mloc[i];
    }
    __syncthreads();
    if (tid < 128) {
      float m = -INFINITY;
#pragma unroll
      for (int k = 0; k < 16; ++k) m = fmaxf(m, red[tid * 16 + k]);
      gct_part[((size_t)b * 128 + tid) * NT2 + tile] = m;
    }
  }
}

// ---------------------------------------------------------------------------
// Kernel 3: gct = max over tiles; q = tanh(gct @ Wp^T + bp). One block per b.
__global__ void gct_q(const float* __restrict__ gct_part, const float* __restrict__ wp,
                      const float* __restrict__ bp, float* __restrict__ q) {
  int b = blockIdx.x, tid = threadIdx.x;   // 128 threads
  __shared__ float g[128];
  float m = -INFINITY;
  for (int tl = 0; tl < NT2; ++tl) m = fmaxf(m, gct_part[((size_t)b * 128 + tid) * NT2 + tl]);
  g[tid] = m;
  __syncthreads();
  float s = bp[tid];
  for (int c = 0; c < 128; ++c) s = fmaf(g[c], wp[tid * 128 + c], s);
  q[b * 128 + tid] = tanhf(s);
}

// ---------------------------------------------------------------------------
// Kernel 4: gate[t] = sigmoid(sum_c h*q); out_part = per-tile max_t h*gate.
__global__ __launch_bounds__(256) void gate_max(
    const float* __restrict__ hmain, const float* __restrict__ q,
    float* __restrict__ out_part) {
  __shared__ float hl[128 * 68];
  __shared__ float ql[128];
  __shared__ float red[256];
  __shared__ float gl[64];
  int tid = threadIdx.x, tile = blockIdx.x, b = blockIdx.y;
  int t0 = tile * 64;
  for (int g = tid; g < 8192; g += 256) {
    int c = g >> 6, t = g & 63;
    hl[c * 68 + t] = (t0 + t < TOUT) ? hmain[((size_t)b * 128 + c) * TOUT + t0 + t] : 0.f;
  }
  if (tid < 128) ql[tid] = q[b * 128 + tid];
  __syncthreads();
  {
    int t = tid & 63, cy = tid >> 6;
    float s = 0.f;
#pragma unroll
    for (int cc = 0; cc < 32; ++cc) s = fmaf(hl[(cy * 32 + cc) * 68 + t], ql[cy * 32 + cc], s);
    red[cy * 64 + t] = s;
  }
  __syncthreads();
  if (tid < 64) {
    float s = red[tid] + red[64 + tid] + red[128 + tid] + red[192 + tid];
    gl[tid] = sigmoidf_(s);
  }
  __syncthreads();
  {
    int c = tid >> 1, th = tid & 1;
    float m = -INFINITY;
#pragma unroll
    for (int tt = 0; tt < 32; ++tt) {
      int t = th * 32 + tt;
      if (t0 + t < TOUT) m = fmaxf(m, hl[c * 68 + t] * gl[t]);
    }
    red[c * 2 + th] = m;
  }
  __syncthreads();
  if (tid < 128) out_part[((size_t)b * 128 + tid) * NT2 + tile] = fmaxf(red[tid * 2], red[tid * 2 + 1]);
}

// ---------------------------------------------------------------------------
// Kernel 5: final max over tiles -> d_out (B,C) row-major.
__global__ void final_max(const float* __restrict__ out_part, float* __restrict__ out) {
  int idx = blockIdx.x * 256 + threadIdx.x;
  if (idx < 512) {
    float m = -INFINITY;
    for (int tl = 0; tl < NT2; ++tl) m = fmaxf(m, out_part[(size_t)idx * NT2 + tl]);
    out[idx] = m;
  }
}

// ---------------------------------------------------------------------------
extern "C" void kernel_launch(void* const* d_in, const int* in_sizes, int n_in,
                              void* d_out, int out_size, void* d_ws, size_t ws_size,
                              hipStream_t stream) {
  const float* x      = (const float*)d_in[0];
  const float* ctx_w  = (const float*)d_in[1];
  const float* ctx_b  = (const float*)d_in[2];
  const float* ctx_sw = (const float*)d_in[3];
  const float* ctx_sb = (const float*)d_in[4];
  const float* main_w = (const float*)d_in[5];
  const float* main_b = (const float*)d_in[6];
  const float* main_sw= (const float*)d_in[7];
  const float* main_sb= (const float*)d_in[8];
  const float* gp_w   = (const float*)d_in[9];
  const float* gp_b   = (const float*)d_in[10];

  char* w = (char*)d_ws;
  __hip_bfloat16* Wn2 = (__hip_bfloat16*)(w);              // 512*4096*2 = 4,194,304
  float* bias_t  = (float*)(w + 4194304);                  // 512*4 = 2048
  float* u2      = (float*)(w + 4196352);                  // 512*4*TP*4 = 16,023,552
  float* hmain   = (float*)(w + 20219904);                 // 4*128*1953*4 = 3,999,744
  float* gct_part= (float*)(w + 24219648);                 // 4*128*31*4 = 63,488
  float* q       = (float*)(w + 24283136);                 // 512*4
  float* out_part= (float*)(w + 24285184);                 // 63,488

  prep_inputs<<<NCH, 256, 0, stream>>>(ctx_w, ctx_b, main_w, main_b, Wn2, bias_t);
  mfma_gemm<<<256, 512, 0, stream>>>(x, Wn2, u2);
  share_act<<<dim3(NT2, B_, 2), 256, 0, stream>>>(u2, bias_t, ctx_sw, ctx_sb,
                                                  main_sw, main_sb, hmain, gct_part);
  gct_q<<<B_, 128, 0, stream>>>(gct_part, gp_w, gp_b, q);
  gate_max<<<dim3(NT2, B_), 256, 0, stream>>>(hmain, q, out_part);
  final_max<<<2, 256, 0, stream>>>(out_part, (float*)d_out);
}

// Round 6
// 310.919 us; speedup vs baseline: 1.3663x; 1.0945x over previous
//
#include <hip/hip_runtime.h>
#include <hip/hip_bf16.h>
#include <cmath>

// Problem constants
#define B_    4
#define T_    1000000
#define E_    8
#define C_    128
#define NCH   512        // fused conv output channels (both branches, 2*256)
#define KK    4096       // GEMM K = E * kernel (8*512); windows are contiguous rows
#define TOUT  1953       // (1e6 - 512)/512 + 1
#define TP    1956       // padded t stride (mult of 4) for aligned float4 stores
#define NT2   31         // ceil(1953/64) tiles of 64 along t

typedef __attribute__((ext_vector_type(8))) short bf16x8;   // 8 bf16 = 4 VGPRs
typedef __attribute__((ext_vector_type(4))) float f32x4;

__device__ __forceinline__ float sigmoidf_(float v) { return 1.f / (1.f + __expf(-v)); }

// async 16B/lane global->LDS copy: LDS dest = uniform base + lane*16.
// GLOBAL source is per-lane (guide: pre-swizzled-source pattern, m173).
__device__ __forceinline__ void gload_lds16(const void* g, void* l) {
  __builtin_amdgcn_global_load_lds(
      (const __attribute__((address_space(1))) void*)g,
      (__attribute__((address_space(3))) void*)l, 16, 0, 0);
}

// ---------------------------------------------------------------------------
// Weight prep (x conversion is fused into the GEMM — stride==kernel so conv
// windows are non-overlapping and the A matrix is a pure reshape of x).
// Frag chunk = 16 rows x 32 k as [lane][8], lane = (k>>3&3)*16 + (row&15).
// Wn2: [nt=n/16][kc=k/32][lane][8]
__global__ __launch_bounds__(256) void prep_inputs(
    const float* __restrict__ wc, const float* __restrict__ bc,
    const float* __restrict__ wm, const float* __restrict__ bm,
    __hip_bfloat16* __restrict__ Wn2, float* __restrict__ bias_t) {
  __shared__ float row[KK];
  const int n = blockIdx.x, br = n >> 8, o = n & 255;
  const float* wsrc = (br ? wm : wc) + (size_t)o * KK;
  for (int i = threadIdx.x; i < KK; i += 256) row[i] = wsrc[i];   // [e][kpos]
  __syncthreads();
  const int nt = n >> 4, nr = n & 15;
  for (int k = threadIdx.x; k < KK; k += 256) {
    int kpos = k >> 3, e = k & 7;                 // W[n][k] with k = kpos*8+e
    size_t addr = (((size_t)nt * 128 + (k >> 5)) * 64
                   + (size_t)((k >> 3) & 3) * 16 + nr) * 8 + (k & 7);
    Wn2[addr] = __float2bfloat16(row[e * 512 + kpos]);
  }
  if (threadIdx.x == 0) bias_t[n] = (br ? bm : bc)[o];
}

// ---------------------------------------------------------------------------
// Kernel C (R10): R5 mechanics + 2 blocks/CU via K-split.
// R5 diagnosis: 4875 cyc/step vs ~1600 compute — the vmcnt(0) barrier
// serializes staging service+latency against compute, and at 1 block/CU
// (grid 256, LDS 96KB) there is NO co-resident work to hide it (m114/m97:
// the ~900TF structure relied on ~3 blocks/CU of implicit overlap).
// Fix: split K in two (kb=0,1), grid 512 = 16tblk x 4b x 4nb x 2kb, BK=32
// -> LDS 2*(16KB A fp32 + 8KB B bf16) = 48KB -> 2 blocks/CU
// (__launch_bounds__(512,4)). While one block drains its barrier, its twin
// computes. Partial sums land in u2a/u2b; share_act adds them on load.
// All staging remains global_load_lds (void result -> LLVM cannot sink it;
// R4's VGPR=48 proved VGPR-destination prefetch rings get eliminated).
//   A: raw fp32 [128 rows][32 k] per buf; cvt fp32->bf16 at consume time.
//      Bank fix (rule #21, both-sides-or-neither): LDS linear; per-lane
//      global source carries unit u = (l&7)^((l>>3)&7); frag read XORs the
//      same involution p0 = ((lane>>4)*2)^(row&7).
//   B: frag-ordered bf16 chunks, 1 gload/wave/step, stride-1 reads.
// Loop: STAGE(next) -> COMPUTE(cur) -> __syncthreads. 64 steps (K=2048).
// XCD swizzle: all 8 (nb,kb) blocks of one (t,b) x-panel share L%8 = XCD ->
// panel fetched from HBM once per XCD, L2-served 7x.
__global__ __launch_bounds__(512, 4) void mfma_gemm(
    const float* __restrict__ x, const __hip_bfloat16* __restrict__ Wn2,
    float* __restrict__ u2a, float* __restrict__ u2b) {
  __shared__ float Aldf[2][4096];          // 2 x 16 KB fp32 A-tile [128][32]
  __shared__ __hip_bfloat16 Bs[2][4096];   // 2 x 8 KB bf16 frag-chunks

  const int tid  = threadIdx.x;
  const int lane = tid & 63, wave = tid >> 6;
  const int wt = wave & 3, wn = wave >> 2;

  // L = xcd + 8*(inner + 8*sh); inner = nb*2+kb; group s = sh*8 + xcd.
  const int L    = blockIdx.x;
  const int xcd  = L & 7;
  const int r    = L >> 3;
  const int inner= r & 7;
  const int nb   = inner >> 1;
  const int kb   = inner & 1;
  const int sh   = r >> 3;                // 0..7
  const int s    = sh * 8 + xcd;          // 0..63
  const int tblk = s & 15, b = s >> 4;
  const int t0 = tblk * 128, n0 = nb * 128;
  const int kbase = kb * 2048;            // float offset within x row

  // ---- A staging: wave stages chunks m = wave*2+q (8 rows each).
  // Lane l of chunk m: row rl = m*8 + (l>>3), stored position p = l&7 ->
  // carries logical unit u = p ^ (rl&7) = (l&7) ^ ((l>>3)&7).
  const float* pAsrc[2];
  int dstA[2];
#pragma unroll
  for (int q = 0; q < 2; ++q) {
    int m  = wave * 2 + q;
    int rl = m * 8 + (lane >> 3);
    int u  = (lane & 7) ^ ((lane >> 3) & 7);
    int rt = t0 + rl;
    if (rt >= TOUT) rt = 0;     // tblk=15 tail rows: clamp (never stored)
    pAsrc[q] = x + (size_t)b * 8000000ull + (size_t)rt * KK + kbase + u * 4;
    dstA[q]  = m * 256;         // floats: chunk m = rows [m*8, m*8+8)
  }
  // ---- B staging: wave stages n-group chunk (wave), kc = kb*64 + step.
  const __hip_bfloat16* gB = Wn2
      + ((size_t)(nb * 8 + wave) * 128 + kb * 64) * 512 + (size_t)lane * 8;

  f32x4 acc[2][4];
#pragma unroll
  for (int i = 0; i < 2; ++i)
#pragma unroll
    for (int j = 0; j < 4; ++j) acc[i][j] = (f32x4)(0.0f);

  auto STAGE = [&](int buf, int step) {
#pragma unroll
    for (int q = 0; q < 2; ++q)
      gload_lds16(pAsrc[q] + (size_t)step * 32, &Aldf[buf][dstA[q]]);
    gload_lds16(gB + (size_t)step * 512, &Bs[buf][(size_t)wave * 512]);
  };

  auto COMPUTE = [&](int buf) {
    const int lnlo = lane & 15;
    const int p0 = ((lane >> 4) * 2) ^ (lnlo & 7);   // swizzled 16B-unit
    bf16x8 aF[2], bF[4];
#pragma unroll
    for (int i = 0; i < 2; ++i) {
      const int Rb = wt * 32 + i * 16 + lnlo;        // tile-local A row
      const float* base = &Aldf[buf][Rb * 32];
      f32x4 q0 = *(const f32x4*)(base + (p0)     * 4);   // logical k 0..3
      f32x4 q1 = *(const f32x4*)(base + (p0 ^ 1) * 4);   // logical k 4..7
      union { __hip_bfloat16 h[8]; bf16x8 v; } u_;
      u_.h[0] = __float2bfloat16(q0[0]); u_.h[1] = __float2bfloat16(q0[1]);
      u_.h[2] = __float2bfloat16(q0[2]); u_.h[3] = __float2bfloat16(q0[3]);
      u_.h[4] = __float2bfloat16(q1[0]); u_.h[5] = __float2bfloat16(q1[1]);
      u_.h[6] = __float2bfloat16(q1[2]); u_.h[7] = __float2bfloat16(q1[3]);
      aF[i] = u_.v;
    }
#pragma unroll
    for (int j = 0; j < 4; ++j)
      bF[j] = *(const bf16x8*)(&Bs[buf][(size_t)(wn * 4 + j) * 512
                                        + (size_t)lane * 8]);
#pragma unroll
    for (int i = 0; i < 2; ++i)
#pragma unroll
      for (int j = 0; j < 4; ++j)
        acc[i][j] = __builtin_amdgcn_mfma_f32_16x16x32_bf16(aF[i], bF[j],
                                                            acc[i][j], 0, 0, 0);
  };

  // Prologue: fill buffer 0 (barrier drains vmcnt per __syncthreads semantics).
  STAGE(0, 0);
  __syncthreads();

  int cur = 0;
#pragma unroll 1
  for (int step = 0; step < 64; ++step) {
    if (step + 1 < 64) STAGE(cur ^ 1, step + 1);  // issue next-tile loads first
    COMPUTE(cur);                                  // ds_read + cvt + 8 MFMA
    __syncthreads();                               // drains vmcnt(0)+lgkmcnt(0)
    cur ^= 1;
  }

  // Epilogue. C/D layout: col = lane&15, row = (lane>>4)*4 + reg.
  float* u2 = kb ? u2b : u2a;
  const int crow = (lane >> 4) * 4;
  const int ccol = lane & 15;
#pragma unroll
  for (int j = 0; j < 4; ++j) {
    int n = n0 + wn * 64 + j * 16 + ccol;
    float* urow = u2 + ((size_t)n * B_ + b) * TP;
#pragma unroll
    for (int i = 0; i < 2; ++i) {
      int t = t0 + wt * 32 + i * 16 + crow;    // mult of 4
      if (t < TOUT) *(f32x4*)(urow + t) = acc[i][j];  // may touch pad [1953,1956)
    }
  }
}

// ---------------------------------------------------------------------------
// Kernel 2: bias + GLU (on load from u2a+u2b partials) -> 1x1 share conv +
// leaky. br==1: store h_main; br==0: per-tile max over t -> gct_part.
__global__ __launch_bounds__(256) void share_act(
    const float* __restrict__ u2a, const float* __restrict__ u2b,
    const float* __restrict__ bias_t,
    const float* __restrict__ wsc, const float* __restrict__ bsc,
    const float* __restrict__ wsm, const float* __restrict__ bsm,
    float* __restrict__ hmain, float* __restrict__ gct_part) {
  __shared__ float Wl[128 * 132];   // Wl[cp*132 + cout] = ws[cout, cp]
  __shared__ float ul[128 * 68];    // ul[cp*68 + t]
  const int tid  = threadIdx.x;
  const int tile = blockIdx.x;      // 0..30
  const int b    = blockIdx.y;
  const int br   = blockIdx.z;
  const int t0   = tile * 64;
  const float* ws = br ? wsm : wsc;
  const float* bs = br ? bsm : bsc;

  for (int g = tid; g < 16384; g += 256) {
    int co = g >> 7, cp = g & 127;
    Wl[cp * 132 + co] = ws[g];
  }
  const size_t base_v = ((size_t)(br * 256) * B_ + b) * TP;
  const size_t base_g = ((size_t)(br * 256 + 128) * B_ + b) * TP;
  for (int g = tid; g < 8192; g += 256) {
    int cp = g >> 6, t = g & 63;
    float v = 0.f;
    if (t0 + t < TOUT) {
      size_t ia = base_v + (size_t)cp * B_ * TP + t0 + t;
      size_t ig = base_g + (size_t)cp * B_ * TP + t0 + t;
      float va = u2a[ia] + u2b[ia] + bias_t[br * 256 + cp];
      float vg = u2a[ig] + u2b[ig] + bias_t[br * 256 + 128 + cp];
      v = va * sigmoidf_(vg);
    }
    ul[cp * 68 + t] = v;
  }
  __syncthreads();

  const int ty = tid >> 4, tx = tid & 15;  // c-groups x t-groups
  float acc[8][4];
#pragma unroll
  for (int i = 0; i < 8; ++i)
#pragma unroll
    for (int j = 0; j < 4; ++j) acc[i][j] = 0.f;

  for (int cp = 0; cp < 128; ++cp) {
    float4 a0 = *(const float4*)&Wl[cp*132 + ty*4];
    float4 a1 = *(const float4*)&Wl[cp*132 + 64 + ty*4];
    float4 b4 = *(const float4*)&ul[cp*68 + tx*4];
    float av[8] = {a0.x,a0.y,a0.z,a0.w,a1.x,a1.y,a1.z,a1.w};
    float bv[4] = {b4.x,b4.y,b4.z,b4.w};
#pragma unroll
    for (int i = 0; i < 8; ++i)
#pragma unroll
      for (int j = 0; j < 4; ++j) acc[i][j] = fmaf(av[i], bv[j], acc[i][j]);
  }

  float mloc[8];
#pragma unroll
  for (int i = 0; i < 8; ++i) mloc[i] = -INFINITY;
#pragma unroll
  for (int i = 0; i < 8; ++i) {
    int c = (i < 4) ? (ty*4 + i) : (64 + ty*4 + (i - 4));
    float bias = bs[c];
#pragma unroll
    for (int j = 0; j < 4; ++j) {
      int t = t0 + tx*4 + j;
      if (t >= TOUT) continue;
      float v = acc[i][j] + bias;
      v = (v >= 0.f) ? v : 0.01f * v;
      if (br == 1) {
        hmain[((size_t)b * 128 + c) * TOUT + t] = v;
      } else {
        mloc[i] = fmaxf(mloc[i], v);
      }
    }
  }
  if (br == 0) {
    __syncthreads();               // done reading ul; reuse as reduction buffer
    float* red = ul;               // 128*16 region
#pragma unroll
    for (int i = 0; i < 8; ++i) {
      int c = (i < 4) ? (ty*4 + i) : (64 + ty*4 + (i - 4));
      red[c * 16 + tx] = mloc[i];
    }
    __syncthreads();
    if (tid < 128) {
      float m = -INFINITY;
#pragma unroll
      for (int k = 0; k < 16; ++k) m = fmaxf(m, red[tid * 16 + k]);
      gct_part[((size_t)b * 128 + tid) * NT2 + tile] = m;
    }
  }
}

// ---------------------------------------------------------------------------
// Kernel 3: gct = max over tiles; q = tanh(gct @ Wp^T + bp). One block per b.
__global__ void gct_q(const float* __restrict__ gct_part, const float* __restrict__ wp,
                      const float* __restrict__ bp, float* __restrict__ q) {
  int b = blockIdx.x, tid = threadIdx.x;   // 128 threads
  __shared__ float g[128];
  float m = -INFINITY;
  for (int tl = 0; tl < NT2; ++tl) m = fmaxf(m, gct_part[((size_t)b * 128 + tid) * NT2 + tl]);
  g[tid] = m;
  __syncthreads();
  float s = bp[tid];
  for (int c = 0; c < 128; ++c) s = fmaf(g[c], wp[tid * 128 + c], s);
  q[b * 128 + tid] = tanhf(s);
}

// ---------------------------------------------------------------------------
// Kernel 4: gate[t] = sigmoid(sum_c h*q); out_part = per-tile max_t h*gate.
__global__ __launch_bounds__(256) void gate_max(
    const float* __restrict__ hmain, const float* __restrict__ q,
    float* __restrict__ out_part) {
  __shared__ float hl[128 * 68];
  __shared__ float ql[128];
  __shared__ float red[256];
  __shared__ float gl[64];
  int tid = threadIdx.x, tile = blockIdx.x, b = blockIdx.y;
  int t0 = tile * 64;
  for (int g = tid; g < 8192; g += 256) {
    int c = g >> 6, t = g & 63;
    hl[c * 68 + t] = (t0 + t < TOUT) ? hmain[((size_t)b * 128 + c) * TOUT + t0 + t] : 0.f;
  }
  if (tid < 128) ql[tid] = q[b * 128 + tid];
  __syncthreads();
  {
    int t = tid & 63, cy = tid >> 6;
    float s = 0.f;
#pragma unroll
    for (int cc = 0; cc < 32; ++cc) s = fmaf(hl[(cy * 32 + cc) * 68 + t], ql[cy * 32 + cc], s);
    red[cy * 64 + t] = s;
  }
  __syncthreads();
  if (tid < 64) {
    float s = red[tid] + red[64 + tid] + red[128 + tid] + red[192 + tid];
    gl[tid] = sigmoidf_(s);
  }
  __syncthreads();
  {
    int c = tid >> 1, th = tid & 1;
    float m = -INFINITY;
#pragma unroll
    for (int tt = 0; tt < 32; ++tt) {
      int t = th * 32 + tt;
      if (t0 + t < TOUT) m = fmaxf(m, hl[c * 68 + t] * gl[t]);
    }
    red[c * 2 + th] = m;
  }
  __syncthreads();
  if (tid < 128) out_part[((size_t)b * 128 + tid) * NT2 + tile] = fmaxf(red[tid * 2], red[tid * 2 + 1]);
}

// ---------------------------------------------------------------------------
// Kernel 5: final max over tiles -> d_out (B,C) row-major.
__global__ void final_max(const float* __restrict__ out_part, float* __restrict__ out) {
  int idx = blockIdx.x * 256 + threadIdx.x;
  if (idx < 512) {
    float m = -INFINITY;
    for (int tl = 0; tl < NT2; ++tl) m = fmaxf(m, out_part[(size_t)idx * NT2 + tl]);
    out[idx] = m;
  }
}

// ---------------------------------------------------------------------------
extern "C" void kernel_launch(void* const* d_in, const int* in_sizes, int n_in,
                              void* d_out, int out_size, void* d_ws, size_t ws_size,
                              hipStream_t stream) {
  const float* x      = (const float*)d_in[0];
  const float* ctx_w  = (const float*)d_in[1];
  const float* ctx_b  = (const float*)d_in[2];
  const float* ctx_sw = (const float*)d_in[3];
  const float* ctx_sb = (const float*)d_in[4];
  const float* main_w = (const float*)d_in[5];
  const float* main_b = (const float*)d_in[6];
  const float* main_sw= (const float*)d_in[7];
  const float* main_sb= (const float*)d_in[8];
  const float* gp_w   = (const float*)d_in[9];
  const float* gp_b   = (const float*)d_in[10];

  char* w = (char*)d_ws;
  __hip_bfloat16* Wn2 = (__hip_bfloat16*)(w);              // 512*4096*2 = 4,194,304
  float* bias_t  = (float*)(w + 4194304);                  // 512*4 = 2048
  float* u2a     = (float*)(w + 4196352);                  // 512*4*TP*4 = 16,023,552
  float* u2b     = (float*)(w + 20219904);                 // 16,023,552
  float* hmain   = (float*)(w + 36243456);                 // 4*128*1953*4 = 3,999,744
  float* gct_part= (float*)(w + 40243200);                 // 4*128*31*4 = 63,488
  float* q       = (float*)(w + 40306688);                 // 512*4
  float* out_part= (float*)(w + 40308736);                 // 63,488

  prep_inputs<<<NCH, 256, 0, stream>>>(ctx_w, ctx_b, main_w, main_b, Wn2, bias_t);
  mfma_gemm<<<512, 512, 0, stream>>>(x, Wn2, u2a, u2b);
  share_act<<<dim3(NT2, B_, 2), 256, 0, stream>>>(u2a, u2b, bias_t, ctx_sw, ctx_sb,
                                                  main_sw, main_sb, hmain, gct_part);
  gct_q<<<B_, 128, 0, stream>>>(gct_part, gp_w, gp_b, q);
  gate_max<<<dim3(NT2, B_), 256, 0, stream>>>(hmain, q, out_part);
  final_max<<<2, 256, 0, stream>>>(out_part, (float*)d_out);
}

// Round 8
// 307.672 us; speedup vs baseline: 1.3807x; 1.0106x over previous
//
#include <hip/hip_runtime.h>
#include <hip/hip_bf16.h>
#include <cmath>

// Problem constants
#define B_    4
#define T_    1000000
#define E_    8
#define C_    128
#define NCH   512        // fused conv output channels (both branches, 2*256)
#define KK    4096       // GEMM K = E * kernel (8*512); windows are contiguous rows
#define TOUT  1953       // (1e6 - 512)/512 + 1
#define TP    1956       // padded t stride (mult of 4) for aligned float4 stores
#define NT2   31         // ceil(1953/64) tiles of 64 along t

typedef __attribute__((ext_vector_type(8))) short bf16x8;   // 8 bf16 = 4 VGPRs
typedef __attribute__((ext_vector_type(4))) float f32x4;

__device__ __forceinline__ float sigmoidf_(float v) { return 1.f / (1.f + __expf(-v)); }

// async 16B/lane global->LDS copy: LDS dest = uniform base + lane*16.
// GLOBAL source is per-lane (guide: pre-swizzled-source pattern, m173).
__device__ __forceinline__ void gload_lds16(const void* g, void* l) {
  __builtin_amdgcn_global_load_lds(
      (const __attribute__((address_space(1))) void*)g,
      (__attribute__((address_space(3))) void*)l, 16, 0, 0);
}

// ---------------------------------------------------------------------------
// Weight prep (x conversion is fused into the GEMM — stride==kernel so conv
// windows are non-overlapping and the A matrix is a pure reshape of x).
// Frag chunk = 16 rows x 32 k as [lane][8], lane = (k>>3&3)*16 + (row&15).
// Wn2: [nt=n/16][kc=k/32][lane][8]
__global__ __launch_bounds__(256) void prep_inputs(
    const float* __restrict__ wc, const float* __restrict__ bc,
    const float* __restrict__ wm, const float* __restrict__ bm,
    __hip_bfloat16* __restrict__ Wn2, float* __restrict__ bias_t) {
  __shared__ float row[KK];
  const int n = blockIdx.x, br = n >> 8, o = n & 255;
  const float* wsrc = (br ? wm : wc) + (size_t)o * KK;
  for (int i = threadIdx.x; i < KK; i += 256) row[i] = wsrc[i];   // [e][kpos]
  __syncthreads();
  const int nt = n >> 4, nr = n & 15;
  for (int k = threadIdx.x; k < KK; k += 256) {
    int kpos = k >> 3, e = k & 7;                 // W[n][k] with k = kpos*8+e
    size_t addr = (((size_t)nt * 128 + (k >> 5)) * 64
                   + (size_t)((k >> 3) & 3) * 16 + nr) * 8 + (k & 7);
    Wn2[addr] = __float2bfloat16(row[e * 512 + kpos]);
  }
  if (threadIdx.x == 0) bias_t[n] = (br ? bm : bc)[o];
}

// ---------------------------------------------------------------------------
// Kernel C (R12 = R11 hardened): counted-vmcnt 3-buffer ring (T3/T4), with
// __builtin_amdgcn_s_barrier() (the m201-template barrier — known not to
// auto-drain vmcnt) instead of raw asm s_barrier.
// R10 diagnosis: per-step __syncthreads drains vmcnt(0) -> every step exposes
// a full L2/HBM round trip; twin-block TLP covers only ~half (101us vs ~37us
// LDS floor). Fix (m218: counted-vs-drain0 = +38-73%): 3-buf ring staged 2
// steps ahead, barrier + s_waitcnt vmcnt(3) -> 3 staging ops (2 A + 1 B per
// wave) stay in flight ACROSS each barrier.
//   Ledger per step t (3 gloads/wave/STAGE, in-order vmcnt retirement):
//     enter: {S(t),S(t+1)} = 6 in flight
//     s_waitcnt vmcnt(3)  -> retires S(t) (the 3 oldest)
//     s_barrier           -> all waves' S(t) landed; buf t%3 ready
//     STAGE((t+2)%3, t+2) -> 6 in flight
//     COMPUTE(t%3)        -> ds_read + cvt + 8 MFMA
//   WAR safety: S(t+2) overwrites buf (t-1)%3; every wave's ds_reads of that
//   buf completed before its step-(t-1) MFMAs (compiler lgkm waits), which
//   precede barrier(t) -> done block-wide.
//   Tail: staged step clamped to 63 (redundant re-stage, never read).
// LDS 3*(16KB A fp32 + 8KB B bf16) = 72KB -> still 2 blocks/CU (144<=160).
// Everything else identical to R10: K-split kb=0/1 (grid 512, u2a/u2b
// partials), A raw fp32 + consume-time cvt, rule-#21 XOR involution on the
// A source/read pair, B frag-ordered, XCD swizzle groups the 8 (nb,kb)
// blocks of one (t,b) x-panel on one XCD.
__global__ __launch_bounds__(512, 4) void mfma_gemm(
    const float* __restrict__ x, const __hip_bfloat16* __restrict__ Wn2,
    float* __restrict__ u2a, float* __restrict__ u2b) {
  __shared__ float Aldf[3][4096];          // 3 x 16 KB fp32 A-tile [128][32]
  __shared__ __hip_bfloat16 Bs[3][4096];   // 3 x 8 KB bf16 frag-chunks

  const int tid  = threadIdx.x;
  const int lane = tid & 63, wave = tid >> 6;
  const int wt = wave & 3, wn = wave >> 2;

  // L = xcd + 8*(inner + 8*sh); inner = nb*2+kb; group s = sh*8 + xcd.
  const int L    = blockIdx.x;
  const int xcd  = L & 7;
  const int r    = L >> 3;
  const int inner= r & 7;
  const int nb   = inner >> 1;
  const int kb   = inner & 1;
  const int sh   = r >> 3;                // 0..7
  const int s    = sh * 8 + xcd;          // 0..63
  const int tblk = s & 15, b = s >> 4;
  const int t0 = tblk * 128, n0 = nb * 128;
  const int kbase = kb * 2048;            // float offset within x row

  // ---- A staging: wave stages chunks m = wave*2+q (8 rows each).
  // Lane l of chunk m: row rl = m*8 + (l>>3), stored position p = l&7 ->
  // carries logical unit u = p ^ (rl&7) = (l&7) ^ ((l>>3)&7).
  const float* pAsrc[2];
  int dstA[2];
#pragma unroll
  for (int q = 0; q < 2; ++q) {
    int m  = wave * 2 + q;
    int rl = m * 8 + (lane >> 3);
    int u  = (lane & 7) ^ ((lane >> 3) & 7);
    int rt = t0 + rl;
    if (rt >= TOUT) rt = 0;     // tblk=15 tail rows: clamp (never stored)
    pAsrc[q] = x + (size_t)b * 8000000ull + (size_t)rt * KK + kbase + u * 4;
    dstA[q]  = m * 256;         // floats: chunk m = rows [m*8, m*8+8)
  }
  // ---- B staging: wave stages n-group chunk (wave), kc = kb*64 + step.
  const __hip_bfloat16* gB = Wn2
      + ((size_t)(nb * 8 + wave) * 128 + kb * 64) * 512 + (size_t)lane * 8;

  f32x4 acc[2][4];
#pragma unroll
  for (int i = 0; i < 2; ++i)
#pragma unroll
    for (int j = 0; j < 4; ++j) acc[i][j] = (f32x4)(0.0f);

  auto STAGE = [&](int buf, int step) {
#pragma unroll
    for (int q = 0; q < 2; ++q)
      gload_lds16(pAsrc[q] + (size_t)step * 32, &Aldf[buf][dstA[q]]);
    gload_lds16(gB + (size_t)step * 512, &Bs[buf][(size_t)wave * 512]);
  };

  auto COMPUTE = [&](int buf) {
    const int lnlo = lane & 15;
    const int p0 = ((lane >> 4) * 2) ^ (lnlo & 7);   // swizzled 16B-unit
    bf16x8 aF[2], bF[4];
#pragma unroll
    for (int i = 0; i < 2; ++i) {
      const int Rb = wt * 32 + i * 16 + lnlo;        // tile-local A row
      const float* base = &Aldf[buf][Rb * 32];
      f32x4 q0 = *(const f32x4*)(base + (p0)     * 4);   // logical k 0..3
      f32x4 q1 = *(const f32x4*)(base + (p0 ^ 1) * 4);   // logical k 4..7
      union { __hip_bfloat16 h[8]; bf16x8 v; } u_;
      u_.h[0] = __float2bfloat16(q0[0]); u_.h[1] = __float2bfloat16(q0[1]);
      u_.h[2] = __float2bfloat16(q0[2]); u_.h[3] = __float2bfloat16(q0[3]);
      u_.h[4] = __float2bfloat16(q1[0]); u_.h[5] = __float2bfloat16(q1[1]);
      u_.h[6] = __float2bfloat16(q1[2]); u_.h[7] = __float2bfloat16(q1[3]);
      aF[i] = u_.v;
    }
#pragma unroll
    for (int j = 0; j < 4; ++j)
      bF[j] = *(const bf16x8*)(&Bs[buf][(size_t)(wn * 4 + j) * 512
                                        + (size_t)lane * 8]);
#pragma unroll
    for (int i = 0; i < 2; ++i)
#pragma unroll
      for (int j = 0; j < 4; ++j)
        acc[i][j] = __builtin_amdgcn_mfma_f32_16x16x32_bf16(aF[i], bF[j],
                                                            acc[i][j], 0, 0, 0);
  };

  // Prologue: stage steps 0,1 into bufs 0,1 -> 6 vmem ops/wave in flight.
  STAGE(0, 0);
  STAGE(1, 1);

  int bc = 0, bsl = 2;   // compute buf (t%3), stage buf ((t+2)%3)
#pragma unroll 1
  for (int step = 0; step < 64; ++step) {
    asm volatile("s_waitcnt vmcnt(3)" ::: "memory");   // retire S(t) only
    __builtin_amdgcn_sched_barrier(0);
    __builtin_amdgcn_s_barrier();                      // buf t%3 ready everywhere
    int ps = step + 2; if (ps > 63) ps = 63;           // tail: redundant clamp
    STAGE(bsl, ps);                                    // 3 ops -> 6 in flight
    COMPUTE(bc);                                       // ds_read + cvt + 8 MFMA
    bc  = (bc  == 2) ? 0 : bc  + 1;
    bsl = (bsl == 2) ? 0 : bsl + 1;
  }

  // Epilogue. C/D layout: col = lane&15, row = (lane>>4)*4 + reg.
  float* u2 = kb ? u2b : u2a;
  const int crow = (lane >> 4) * 4;
  const int ccol = lane & 15;
#pragma unroll
  for (int j = 0; j < 4; ++j) {
    int n = n0 + wn * 64 + j * 16 + ccol;
    float* urow = u2 + ((size_t)n * B_ + b) * TP;
#pragma unroll
    for (int i = 0; i < 2; ++i) {
      int t = t0 + wt * 32 + i * 16 + crow;    // mult of 4
      if (t < TOUT) *(f32x4*)(urow + t) = acc[i][j];  // may touch pad [1953,1956)
    }
  }
}

// ---------------------------------------------------------------------------
// Kernel 2: bias + GLU (on load from u2a+u2b partials) -> 1x1 share conv +
// leaky. br==1: store h_main; br==0: per-tile max over t -> gct_part.
__global__ __launch_bounds__(256) void share_act(
    const float* __restrict__ u2a, const float* __restrict__ u2b,
    const float* __restrict__ bias_t,
    const float* __restrict__ wsc, const float* __restrict__ bsc,
    const float* __restrict__ wsm, const float* __restrict__ bsm,
    float* __restrict__ hmain, float* __restrict__ gct_part) {
  __shared__ float Wl[128 * 132];   // Wl[cp*132 + cout] = ws[cout, cp]
  __shared__ float ul[128 * 68];    // ul[cp*68 + t]
  const int tid  = threadIdx.x;
  const int tile = blockIdx.x;      // 0..30
  const int b    = blockIdx.y;
  const int br   = blockIdx.z;
  const int t0   = tile * 64;
  const float* ws = br ? wsm : wsc;
  const float* bs = br ? bsm : bsc;

  for (int g = tid; g < 16384; g += 256) {
    int co = g >> 7, cp = g & 127;
    Wl[cp * 132 + co] = ws[g];
  }
  const size_t base_v = ((size_t)(br * 256) * B_ + b) * TP;
  const size_t base_g = ((size_t)(br * 256 + 128) * B_ + b) * TP;
  for (int g = tid; g < 8192; g += 256) {
    int cp = g >> 6, t = g & 63;
    float v = 0.f;
    if (t0 + t < TOUT) {
      size_t ia = base_v + (size_t)cp * B_ * TP + t0 + t;
      size_t ig = base_g + (size_t)cp * B_ * TP + t0 + t;
      float va = u2a[ia] + u2b[ia] + bias_t[br * 256 + cp];
      float vg = u2a[ig] + u2b[ig] + bias_t[br * 256 + 128 + cp];
      v = va * sigmoidf_(vg);
    }
    ul[cp * 68 + t] = v;
  }
  __syncthreads();

  const int ty = tid >> 4, tx = tid & 15;  // c-groups x t-groups
  float acc[8][4];
#pragma unroll
  for (int i = 0; i < 8; ++i)
#pragma unroll
    for (int j = 0; j < 4; ++j) acc[i][j] = 0.f;

  for (int cp = 0; cp < 128; ++cp) {
    float4 a0 = *(const float4*)&Wl[cp*132 + ty*4];
    float4 a1 = *(const float4*)&Wl[cp*132 + 64 + ty*4];
    float4 b4 = *(const float4*)&ul[cp*68 + tx*4];
    float av[8] = {a0.x,a0.y,a0.z,a0.w,a1.x,a1.y,a1.z,a1.w};
    float bv[4] = {b4.x,b4.y,b4.z,b4.w};
#pragma unroll
    for (int i = 0; i < 8; ++i)
#pragma unroll
      for (int j = 0; j < 4; ++j) acc[i][j] = fmaf(av[i], bv[j], acc[i][j]);
  }

  float mloc[8];
#pragma unroll
  for (int i = 0; i < 8; ++i) mloc[i] = -INFINITY;
#pragma unroll
  for (int i = 0; i < 8; ++i) {
    int c = (i < 4) ? (ty*4 + i) : (64 + ty*4 + (i - 4));
    float bias = bs[c];
#pragma unroll
    for (int j = 0; j < 4; ++j) {
      int t = t0 + tx*4 + j;
      if (t >= TOUT) continue;
      float v = acc[i][j] + bias;
      v = (v >= 0.f) ? v : 0.01f * v;
      if (br == 1) {
        hmain[((size_t)b * 128 + c) * TOUT + t] = v;
      } else {
        mloc[i] = fmaxf(mloc[i], v);
      }
    }
  }
  if (br == 0) {
    __syncthreads();               // done reading ul; reuse as reduction buffer
    float* red = ul;               // 128*16 region
#pragma unroll
    for (int i = 0; i < 8; ++i) {
      int c = (i < 4) ? (ty*4 + i) : (64 + ty*4 + (i - 4));
      red[c * 16 + tx] = mloc[i];
    }
    __syncthreads();
    if (tid < 128) {
      float m = -INFINITY;
#pragma unroll
      for (int k = 0; k < 16; ++k) m = fmaxf(m, red[tid * 16 + k]);
      gct_part[((size_t)b * 128 + tid) * NT2 + tile] = m;
    }
  }
}

// ---------------------------------------------------------------------------
// Kernel 3: gct = max over tiles; q = tanh(gct @ Wp^T + bp). One block per b.
__global__ void gct_q(const float* __restrict__ gct_part, const float* __restrict__ wp,
                      const float* __restrict__ bp, float* __restrict__ q) {
  int b = blockIdx.x, tid = threadIdx.x;   // 128 threads
  __shared__ float g[128];
  float m = -INFINITY;
  for (int tl = 0; tl < NT2; ++tl) m = fmaxf(m, gct_part[((size_t)b * 128 + tid) * NT2 + tl]);
  g[tid] = m;
  __syncthreads();
  float s = bp[tid];
  for (int c = 0; c < 128; ++c) s = fmaf(g[c], wp[tid * 128 + c], s);
  q[b * 128 + tid] = tanhf(s);
}

// ---------------------------------------------------------------------------
// Kernel 4: gate[t] = sigmoid(sum_c h*q); out_part = per-tile max_t h*gate.
__global__ __launch_bounds__(256) void gate_max(
    const float* __restrict__ hmain, const float* __restrict__ q,
    float* __restrict__ out_part) {
  __shared__ float hl[128 * 68];
  __shared__ float ql[128];
  __shared__ float red[256];
  __shared__ float gl[64];
  int tid = threadIdx.x, tile = blockIdx.x, b = blockIdx.y;
  int t0 = tile * 64;
  for (int g = tid; g < 8192; g += 256) {
    int c = g >> 6, t = g & 63;
    hl[c * 68 + t] = (t0 + t < TOUT) ? hmain[((size_t)b * 128 + c) * TOUT + t0 + t] : 0.f;
  }
  if (tid < 128) ql[tid] = q[b * 128 + tid];
  __syncthreads();
  {
    int t = tid & 63, cy = tid >> 6;
    float s = 0.f;
#pragma unroll
    for (int cc = 0; cc < 32; ++cc) s = fmaf(hl[(cy * 32 + cc) * 68 + t], ql[cy * 32 + cc], s);
    red[cy * 64 + t] = s;
  }
  __syncthreads();
  if (tid < 64) {
    float s = red[tid] + red[64 + tid] + red[128 + tid] + red[192 + tid];
    gl[tid] = sigmoidf_(s);
  }
  __syncthreads();
  {
    int c = tid >> 1, th = tid & 1;
    float m = -INFINITY;
#pragma unroll
    for (int tt = 0; tt < 32; ++tt) {
      int t = th * 32 + tt;
      if (t0 + t < TOUT) m = fmaxf(m, hl[c * 68 + t] * gl[t]);
    }
    red[c * 2 + th] = m;
  }
  __syncthreads();
  if (tid < 128) out_part[((size_t)b * 128 + tid) * NT2 + tile] = fmaxf(red[tid * 2], red[tid * 2 + 1]);
}

// ---------------------------------------------------------------------------
// Kernel 5: final max over tiles -> d_out (B,C) row-major.
__global__ void final_max(const float* __restrict__ out_part, float* __restrict__ out) {
  int idx = blockIdx.x * 256 + threadIdx.x;
  if (idx < 512) {
    float m = -INFINITY;
    for (int tl = 0; tl < NT2; ++tl) m = fmaxf(m, out_part[(size_t)idx * NT2 + tl]);
    out[idx] = m;
  }
}

// ---------------------------------------------------------------------------
extern "C" void kernel_launch(void* const* d_in, const int* in_sizes, int n_in,
                              void* d_out, int out_size, void* d_ws, size_t ws_size,
                              hipStream_t stream) {
  const float* x      = (const float*)d_in[0];
  const float* ctx_w  = (const float*)d_in[1];
  const float* ctx_b  = (const float*)d_in[2];
  const float* ctx_sw = (const float*)d_in[3];
  const float* ctx_sb = (const float*)d_in[4];
  const float* main_w = (const float*)d_in[5];
  const float* main_b = (const float*)d_in[6];
  const float* main_sw= (const float*)d_in[7];
  const float* main_sb= (const float*)d_in[8];
  const float* gp_w   = (const float*)d_in[9];
  const float* gp_b   = (const float*)d_in[10];

  char* w = (char*)d_ws;
  __hip_bfloat16* Wn2 = (__hip_bfloat16*)(w);              // 512*4096*2 = 4,194,304
  float* bias_t  = (float*)(w + 4194304);                  // 512*4 = 2048
  float* u2a     = (float*)(w + 4196352);                  // 512*4*TP*4 = 16,023,552
  float* u2b     = (float*)(w + 20219904);                 // 16,023,552
  float* hmain   = (float*)(w + 36243456);                 // 4*128*1953*4 = 3,999,744
  float* gct_part= (float*)(w + 40243200);                 // 4*128*31*4 = 63,488
  float* q       = (float*)(w + 40306688);                 // 512*4
  float* out_part= (float*)(w + 40308736);                 // 63,488

  prep_inputs<<<NCH, 256, 0, stream>>>(ctx_w, ctx_b, main_w, main_b, Wn2, bias_t);
  mfma_gemm<<<512, 512, 0, stream>>>(x, Wn2, u2a, u2b);
  share_act<<<dim3(NT2, B_, 2), 256, 0, stream>>>(u2a, u2b, bias_t, ctx_sw, ctx_sb,
                                                  main_sw, main_sb, hmain, gct_part);
  gct_q<<<B_, 128, 0, stream>>>(gct_part, gp_w, gp_b, q);
  gate_max<<<dim3(NT2, B_), 256, 0, stream>>>(hmain, q, out_part);
  final_max<<<2, 256, 0, stream>>>(out_part, (float*)d_out);
}